// Round 2
// baseline (215.183 us; speedup 1.0000x reference)
//
#include <hip/hip_runtime.h>

// Tall-skinny GEMM: out[65536,64] = x[65536,512] @ W[512,64], fp32 in/out.
// bf16 MFMA 16x16x32 -> compute ~1.7us at 2.5PF; kernel is a ~151MB stream
// (~24us floor at 6.3TB/s). W prepped once into MFMA B-fragment layout (d_ws),
// staged to LDS once per (persistent) block.
//
// R2 changes vs R1: 4-deep rotating A-prefetch ring (bounded VGPRs, >=6KB/wave
// in flight to cover ~900cyc HBM latency at 2 waves/SIMD occupancy);
// persistent 512-block grid (B staged once per block, not per row-tile).

#define KDIM  512
#define NDIM  64
#define NTILES 1024   // 65536 rows / 64 rows per tile
#define GRID  512     // 2 blocks/CU * 256 CU; each block does 2 tiles

typedef __attribute__((ext_vector_type(8))) short short8;   // 8 bf16 = 4 VGPRs
typedef __attribute__((ext_vector_type(4))) float f32x4;    // MFMA accumulator

__device__ __forceinline__ unsigned short f2bf(float f) {
    // round-to-nearest-even fp32 -> bf16
    unsigned int u = __float_as_uint(f);
    u += 0x7FFFu + ((u >> 16) & 1u);
    return (unsigned short)(u >> 16);
}

// ---------------------------------------------------------------------------
// Prep: W[512,64] fp32 -> bf16 B-fragments in d_ws.
// Slot s = (kt*4 + nt)*64 + lane holds 8 bf16:
//   B[kt*32 + 8*(lane>>4) + j][nt*16 + (lane&15)],  j in [0,8)
// 4096 slots * 16B = 64KB.
// ---------------------------------------------------------------------------
__global__ void prep_w(const float* __restrict__ W, uint4* __restrict__ ws) {
    int t = blockIdx.x * 256 + threadIdx.x;   // 0..4095
    int l = t & 63;
    int ntkt = t >> 6;
    int nt = ntkt & 3, kt = ntkt >> 2;
    int n = nt * 16 + (l & 15);
    int kbase = kt * 32 + (l >> 4) * 8;
    unsigned int p[4];
#pragma unroll
    for (int jj = 0; jj < 4; ++jj) {
        unsigned int lo = f2bf(W[(kbase + 2 * jj    ) * NDIM + n]);
        unsigned int hi = f2bf(W[(kbase + 2 * jj + 1) * NDIM + n]);
        p[jj] = lo | (hi << 16);
    }
    uint4 v; v.x = p[0]; v.y = p[1]; v.z = p[2]; v.w = p[3];
    ws[t] = v;
}

// ---------------------------------------------------------------------------
// Main: 256 thr = 4 waves; block handles 64 rows/tile, wave 16 rows.
// Persistent: each block walks tiles {bid, bid+512}.
// ---------------------------------------------------------------------------
__global__ __launch_bounds__(256, 2) void gemm_tall(
    const float* __restrict__ x, const float* __restrict__ W,
    const uint4* __restrict__ wsB, float* __restrict__ out, int prepped)
{
    __shared__ __align__(16) unsigned short Bl[32768];   // 64KB bf16 B-fragments

    const int tid = threadIdx.x;

    if (prepped) {
        uint4* dst = (uint4*)Bl;
#pragma unroll
        for (int i = 0; i < 16; ++i) dst[tid + i * 256] = wsB[tid + i * 256];
    } else {
        // fallback: gather straight from fp32 W (same layout as prep_w)
        for (int s = tid; s < 4096; s += 256) {
            int l = s & 63;
            int ntkt = s >> 6;
            int nt = ntkt & 3, kt = ntkt >> 2;
            int n = nt * 16 + (l & 15);
            int kbase = kt * 32 + (l >> 4) * 8;
            unsigned short* d = &Bl[s * 8];
#pragma unroll
            for (int j = 0; j < 8; ++j) d[j] = f2bf(W[(kbase + j) * NDIM + n]);
        }
    }
    __syncthreads();

    const int wave = tid >> 6;
    const int lane = tid & 63;
    const int c = lane & 15;          // A row within wave stripe / C col
    const int q = lane >> 4;          // k-quad
    const short8* Bf = (const short8*)Bl;

    for (int tile = blockIdx.x; tile < NTILES; tile += GRID) {
        const int rowBase = tile * 64 + wave * 16;
        const float* xr = x + (size_t)(rowBase + c) * KDIM + q * 8;

        f32x4 acc[4] = {{0.f,0.f,0.f,0.f},{0.f,0.f,0.f,0.f},
                        {0.f,0.f,0.f,0.f},{0.f,0.f,0.f,0.f}};

        // 4-deep rotating prefetch ring: slot s holds A data for step kt
        // with kt % 4 == s. k = kt*32 + q*8 + j, j in [0,8).
        float4 A0[4], A1[4];
#pragma unroll
        for (int i = 0; i < 4; ++i) {
            A0[i] = *(const float4*)(xr + i * 32);
            A1[i] = *(const float4*)(xr + i * 32 + 4);
        }

#pragma unroll
        for (int kt = 0; kt < 16; ++kt) {
            const int s = kt & 3;
            float4 p0 = A0[s], p1 = A1[s];
            if (kt < 12) {
                A0[s] = *(const float4*)(xr + (kt + 4) * 32);
                A1[s] = *(const float4*)(xr + (kt + 4) * 32 + 4);
            }
            short8 af;
            af[0] = (short)f2bf(p0.x); af[1] = (short)f2bf(p0.y);
            af[2] = (short)f2bf(p0.z); af[3] = (short)f2bf(p0.w);
            af[4] = (short)f2bf(p1.x); af[5] = (short)f2bf(p1.y);
            af[6] = (short)f2bf(p1.z); af[7] = (short)f2bf(p1.w);
#pragma unroll
            for (int nt = 0; nt < 4; ++nt) {
                short8 bf = Bf[(kt * 4 + nt) * 64 + lane];
                acc[nt] = __builtin_amdgcn_mfma_f32_16x16x32_bf16(af, bf, acc[nt], 0, 0, 0);
            }
        }

        // C/D layout: col = lane&15, row = 4*(lane>>4) + i   [m89/m91 verified]
#pragma unroll
        for (int nt = 0; nt < 4; ++nt) {
#pragma unroll
            for (int i = 0; i < 4; ++i) {
                out[(size_t)(rowBase + q * 4 + i) * NDIM + nt * 16 + c] = acc[nt][i];
            }
        }
    }
}

extern "C" void kernel_launch(void* const* d_in, const int* in_sizes, int n_in,
                              void* d_out, int out_size, void* d_ws, size_t ws_size,
                              hipStream_t stream) {
    const float* x = (const float*)d_in[0];
    const float* W = (const float*)d_in[1];
    float* out = (float*)d_out;

    if (ws_size >= 65536) {
        prep_w<<<16, 256, 0, stream>>>(W, (uint4*)d_ws);
        gemm_tall<<<GRID, 256, 0, stream>>>(x, W, (const uint4*)d_ws, out, 1);
    } else {
        gemm_tall<<<GRID, 256, 0, stream>>>(x, W, nullptr, out, 0);
    }
}

// Round 3
// 195.981 us; speedup vs baseline: 1.0980x; 1.0980x over previous
//
#include <hip/hip_runtime.h>

// Tall-skinny GEMM: out[65536,64] = x[65536,512] @ W[512,64], fp32 in/out.
// bf16 MFMA 16x16x32 -> compute ~1.7us at 2.5PF; kernel is a ~151MB stream
// (~24us floor at 6.3TB/s). W prepped once into MFMA B-fragment layout (d_ws),
// staged to LDS once per block.
//
// R3: revert persistent grid (R2 regressed +10us). 512-thread blocks, one
// 128-row tile each, grid=512 exact cover. 64KB LDS/block -> 2 blocks/CU ->
// 16 waves/CU (4/SIMD, launch_bounds(512,4) caps VGPR at 128) = 2x the
// latency-hiding of R1/R2. A-prefetch ring issued before LDS staging so HBM
// latency overlaps the staging + barrier.

#define KDIM  512
#define NDIM  64

typedef __attribute__((ext_vector_type(8))) short short8;   // 8 bf16 = 4 VGPRs
typedef __attribute__((ext_vector_type(4))) float f32x4;    // MFMA accumulator

__device__ __forceinline__ unsigned short f2bf(float f) {
    // round-to-nearest-even fp32 -> bf16
    unsigned int u = __float_as_uint(f);
    u += 0x7FFFu + ((u >> 16) & 1u);
    return (unsigned short)(u >> 16);
}

// ---------------------------------------------------------------------------
// Prep: W[512,64] fp32 -> bf16 B-fragments in d_ws.
// Slot s = (kt*4 + nt)*64 + lane holds 8 bf16:
//   B[kt*32 + 8*(lane>>4) + j][nt*16 + (lane&15)],  j in [0,8)
// 4096 slots * 16B = 64KB.
// ---------------------------------------------------------------------------
__global__ void prep_w(const float* __restrict__ W, uint4* __restrict__ ws) {
    int t = blockIdx.x * 256 + threadIdx.x;   // 0..4095
    int l = t & 63;
    int ntkt = t >> 6;
    int nt = ntkt & 3, kt = ntkt >> 2;
    int n = nt * 16 + (l & 15);
    int kbase = kt * 32 + (l >> 4) * 8;
    unsigned int p[4];
#pragma unroll
    for (int jj = 0; jj < 4; ++jj) {
        unsigned int lo = f2bf(W[(kbase + 2 * jj    ) * NDIM + n]);
        unsigned int hi = f2bf(W[(kbase + 2 * jj + 1) * NDIM + n]);
        p[jj] = lo | (hi << 16);
    }
    uint4 v; v.x = p[0]; v.y = p[1]; v.z = p[2]; v.w = p[3];
    ws[t] = v;
}

// ---------------------------------------------------------------------------
// Main: 512 thr = 8 waves; block handles 128 rows, wave 16 rows. grid = 512.
// ---------------------------------------------------------------------------
__global__ __launch_bounds__(512, 4) void gemm_tall(
    const float* __restrict__ x, const float* __restrict__ W,
    const uint4* __restrict__ wsB, float* __restrict__ out, int prepped)
{
    __shared__ __align__(16) unsigned short Bl[32768];   // 64KB bf16 B-fragments

    const int tid  = threadIdx.x;
    const int wave = tid >> 6;
    const int lane = tid & 63;
    const int c = lane & 15;          // A row within wave stripe / C col
    const int q = lane >> 4;          // k-quad
    const int rowBase = blockIdx.x * 128 + wave * 16;
    const float* xr = x + (size_t)(rowBase + c) * KDIM + q * 8;

    // A-prefetch ring, issued BEFORE staging: its HBM latency (~900cyc) hides
    // under the 64KB LDS staging + barrier. Slot s holds data for kt%4==s;
    // k = kt*32 + q*8 + j, j in [0,8).
    float4 A0[4], A1[4];
#pragma unroll
    for (int i = 0; i < 4; ++i) {
        A0[i] = *(const float4*)(xr + i * 32);
        A1[i] = *(const float4*)(xr + i * 32 + 4);
    }

    if (prepped) {
        uint4* dst = (uint4*)Bl;
#pragma unroll
        for (int i = 0; i < 8; ++i) dst[tid + i * 512] = wsB[tid + i * 512];
    } else {
        // fallback: gather straight from fp32 W (same layout as prep_w)
        for (int s = tid; s < 4096; s += 512) {
            int l = s & 63;
            int ntkt = s >> 6;
            int nt = ntkt & 3, kt = ntkt >> 2;
            int n = nt * 16 + (l & 15);
            int kbase = kt * 32 + (l >> 4) * 8;
            unsigned short* d = &Bl[s * 8];
#pragma unroll
            for (int j = 0; j < 8; ++j) d[j] = f2bf(W[(kbase + j) * NDIM + n]);
        }
    }
    __syncthreads();

    const short8* Bf = (const short8*)Bl;

    f32x4 acc[4] = {{0.f,0.f,0.f,0.f},{0.f,0.f,0.f,0.f},
                    {0.f,0.f,0.f,0.f},{0.f,0.f,0.f,0.f}};

#pragma unroll
    for (int kt = 0; kt < 16; ++kt) {
        const int s = kt & 3;
        float4 p0 = A0[s], p1 = A1[s];
        if (kt < 12) {
            A0[s] = *(const float4*)(xr + (kt + 4) * 32);
            A1[s] = *(const float4*)(xr + (kt + 4) * 32 + 4);
        }
        short8 af;
        af[0] = (short)f2bf(p0.x); af[1] = (short)f2bf(p0.y);
        af[2] = (short)f2bf(p0.z); af[3] = (short)f2bf(p0.w);
        af[4] = (short)f2bf(p1.x); af[5] = (short)f2bf(p1.y);
        af[6] = (short)f2bf(p1.z); af[7] = (short)f2bf(p1.w);
#pragma unroll
        for (int nt = 0; nt < 4; ++nt) {
            short8 bf = Bf[(kt * 4 + nt) * 64 + lane];
            acc[nt] = __builtin_amdgcn_mfma_f32_16x16x32_bf16(af, bf, acc[nt], 0, 0, 0);
        }
    }

    // C/D layout: col = lane&15, row = 4*(lane>>4) + i   [m89/m91 verified]
#pragma unroll
    for (int nt = 0; nt < 4; ++nt) {
#pragma unroll
        for (int i = 0; i < 4; ++i) {
            out[(size_t)(rowBase + q * 4 + i) * NDIM + nt * 16 + c] = acc[nt][i];
        }
    }
}

extern "C" void kernel_launch(void* const* d_in, const int* in_sizes, int n_in,
                              void* d_out, int out_size, void* d_ws, size_t ws_size,
                              hipStream_t stream) {
    const float* x = (const float*)d_in[0];
    const float* W = (const float*)d_in[1];
    float* out = (float*)d_out;

    if (ws_size >= 65536) {
        prep_w<<<16, 256, 0, stream>>>(W, (uint4*)d_ws);
        gemm_tall<<<512, 512, 0, stream>>>(x, W, (const uint4*)d_ws, out, 1);
    } else {
        gemm_tall<<<512, 512, 0, stream>>>(x, W, nullptr, out, 0);
    }
}